// Round 1
// 220.547 us; speedup vs baseline: 1.0218x; 1.0218x over previous
//
#include <hip/hip_runtime.h>

typedef __attribute__((ext_vector_type(8))) short bf16x8;  // 8 bf16 = 4 VGPRs (MFMA A/B frag)
typedef __attribute__((ext_vector_type(4))) float f32x4;   // MFMA C/D frag
typedef __attribute__((ext_vector_type(4))) unsigned int u32x4;
typedef unsigned short ushort_t;

constexpr int Dm  = 1024;    // d_model
constexpr int NH  = 16;      // heads
constexpr int HD  = 64;      // head dim
constexpr int SQ  = 2048;    // seq len
constexpr int BB  = 2;       // batch
constexpr int MM  = BB * SQ; // 4096 rows

// fp32 -> bf16 bits, round-to-nearest-even (finite values only)
__device__ __forceinline__ ushort_t f2bf(float f) {
    unsigned int u = __float_as_uint(f);
    u += 0x7FFFu + ((u >> 16) & 1u);
    return (ushort_t)(u >> 16);
}

// async global(16B) -> LDS; lane l lands at readfirstlane(dst)+l*16 [m97/m104]
__device__ __forceinline__ void gld16(const void* g, void* l) {
    __builtin_amdgcn_global_load_lds(
        (const __attribute__((address_space(1))) void*)g,
        (__attribute__((address_space(3))) void*)l, 16, 0, 0);
}

// ---------------------------------------------------------------------------
// One-shot cast of x + 4 weight matrices to bf16.
// ---------------------------------------------------------------------------
__global__ void cast_all(const float4* __restrict__ x,  const float4* __restrict__ qw,
                         const float4* __restrict__ kw, const float4* __restrict__ vw,
                         const float4* __restrict__ ow,
                         uint2* __restrict__ xb,  uint2* __restrict__ qwb,
                         uint2* __restrict__ kwb, uint2* __restrict__ vwb,
                         uint2* __restrict__ owb)
{
    int i = blockIdx.x * 256 + threadIdx.x;
    const float4* src; uint2* dst; int off;
    if      (i < 1048576) { src = x;  dst = xb;  off = i; }
    else if (i < 1310720) { src = qw; dst = qwb; off = i - 1048576; }
    else if (i < 1572864) { src = kw; dst = kwb; off = i - 1310720; }
    else if (i < 1835008) { src = vw; dst = vwb; off = i - 1572864; }
    else                  { src = ow; dst = owb; off = i - 1835008; }
    float4 v = src[off];
    uint2 o;
    o.x = (unsigned)f2bf(v.x) | ((unsigned)f2bf(v.y) << 16);
    o.y = (unsigned)f2bf(v.z) | ((unsigned)f2bf(v.w) << 16);
    dst[off] = o;
}

// ---------------------------------------------------------------------------
// Double-buffered single-barrier MFMA GEMM core.
// C = A(bf16)[M,1024] @ W(bf16,[N,1024])^T + bias. Tile TM x 128, BK=32,
// 256 thr = 4 waves (2x2). Staging via global_load_lds dwordx4, lane-linear.
// ---------------------------------------------------------------------------
template<int TM, typename EPI>
__device__ __forceinline__ void gemm_core(const ushort_t* __restrict__ A,
                                          const ushort_t* __restrict__ W,
                                          const float* __restrict__ bias,
                                          int n0, int m0, EPI epi)
{
    constexpr int AF = TM / 32;            // A frags per wave (wave tile = TM/2 rows)
    __shared__ ushort_t As[2][TM * 32];
    __shared__ ushort_t Ws[2][128 * 32];
    const int t    = threadIdx.x;
    const int lane = t & 63, w = t >> 6;
    const int lm   = lane & 15, quad = lane >> 4;
    const int wm   = w & 1, wn = w >> 1;

    const f32x4 fz = {0.f, 0.f, 0.f, 0.f};
    f32x4 acc[AF][4];
#pragma unroll
    for (int mi = 0; mi < AF; ++mi)
#pragma unroll
        for (int ni = 0; ni < 4; ++ni) acc[mi][ni] = fz;

    float bsv[4];
#pragma unroll
    for (int ni = 0; ni < 4; ++ni) bsv[ni] = bias[n0 + wn * 64 + ni * 16 + lm];

    auto stage = [&](int k0, int b) {
#pragma unroll
        for (int j = 0; j < TM / 64; ++j) {          // A: TM*4 slots of 16B
            int s = t + 256 * j;
            gld16(A + (size_t)(m0 + (s >> 2)) * 1024 + k0 + (s & 3) * 8, &As[b][s * 8]);
        }
#pragma unroll
        for (int j = 0; j < 2; ++j) {                // W: 512 slots
            int s = t + 256 * j;
            gld16(W + (size_t)(n0 + (s >> 2)) * 1024 + k0 + (s & 3) * 8, &Ws[b][s * 8]);
        }
    };

    stage(0, 0);
    int cur = 0;
    for (int k0 = 0; k0 < 1024; k0 += 32) {
        __syncthreads();              // drains buf[cur] loads; frees buf[cur^1]
        if (k0 + 32 < 1024) stage(k0 + 32, cur ^ 1);

        bf16x8 af[AF], bfr[4];
#pragma unroll
        for (int mi = 0; mi < AF; ++mi)
            af[mi] = *(const bf16x8*)&As[cur][(wm * (TM / 2) + mi * 16 + lm) * 32 + quad * 8];
#pragma unroll
        for (int ni = 0; ni < 4; ++ni)
            bfr[ni] = *(const bf16x8*)&Ws[cur][(wn * 64 + ni * 16 + lm) * 32 + quad * 8];
#pragma unroll
        for (int mi = 0; mi < AF; ++mi)
#pragma unroll
            for (int ni = 0; ni < 4; ++ni)
                acc[mi][ni] = __builtin_amdgcn_mfma_f32_16x16x32_bf16(
                                  af[mi], bfr[ni], acc[mi][ni], 0, 0, 0);
        cur ^= 1;
    }

    // C/D layout: col = lane&15, row = quad*4 + reg
#pragma unroll
    for (int mi = 0; mi < AF; ++mi)
#pragma unroll
        for (int ni = 0; ni < 4; ++ni)
#pragma unroll
            for (int r = 0; r < 4; ++r) {
                const int m = m0 + wm * (TM / 2) + mi * 16 + quad * 4 + r;
                const int n = n0 + wn * 64 + ni * 16 + lm;
                epi(m, n, acc[mi][ni][r] + bsv[ni]);
            }
}

__global__ __launch_bounds__(256) void gemm_qkv(
    const ushort_t* __restrict__ xb,
    const ushort_t* __restrict__ qwb, const float* __restrict__ qb,
    const ushort_t* __restrict__ kwb, const float* __restrict__ kb,
    const ushort_t* __restrict__ vwb, const float* __restrict__ vb,
    ushort_t* __restrict__ Qb, ushort_t* __restrict__ Kb, ushort_t* __restrict__ Vb)
{
    const int z = blockIdx.z;
    const ushort_t* W   = (z == 0) ? qwb : (z == 1) ? kwb : vwb;
    const float*    bias = (z == 0) ? qb  : (z == 1) ? kb  : vb;
    ushort_t*       dst  = (z == 0) ? Qb  : (z == 1) ? Kb  : Vb;
    const int n0 = blockIdx.x * 128, m0 = blockIdx.y * 128;
    const bool vt = (z == 2);
    const float qs = (z == 0) ? 0.125f : 1.0f;   // fold 1/sqrt(HD) into Q (exact: pow2)

    gemm_core<128>(xb, W, bias, n0, m0, [&](int m, int n, float v) {
        v *= qs;
        const int b = m >> 11, s = m & 2047, h = n >> 6, hd = n & 63;
        const size_t idx = vt ? ((size_t)((b * NH + h) * 64 + hd) * SQ + s)
                              : ((size_t)((b * NH + h) * SQ + s) * 64 + hd);
        dst[idx] = f2bf(v);
    });
}

__global__ __launch_bounds__(256) void gemm_out(
    const ushort_t* __restrict__ Ab, const ushort_t* __restrict__ owb,
    const float* __restrict__ ob, float* __restrict__ out)
{
    const int n0 = blockIdx.x * 128, m0 = blockIdx.y * 64;
    gemm_core<64>(Ab, owb, ob, n0, m0, [&](int m, int n, float v) {
        out[(size_t)m * 1024 + n] = v;
    });
}

// ---------------------------------------------------------------------------
// Attention v4: swapped-operand scheme (no E LDS strip).
// Block = (b,h) x 64q; 4 waves, each owns 16 q-rows x all keys.
// QK^T computed as S^T = mfma(K, Q): lane holds S^T[key=quad*4+r][q=lm].
// E^T B-frag assembled IN REGISTERS: cvt_pk pairs + ds_swizzle lane^16
// exchange + quad-parity selects. V staged with 8-key chunk permutation
// {0,16,8,24} so A-frag k-order matches. PV: acc^T[d][q] = mfma(V^T, E^T).
// Denominator via ones-A-frag MFMA (row0 = sum of ev per q) - no butterfly.
// Q pre-scaled by 0.125 in gemm_qkv.
// ---------------------------------------------------------------------------
__global__ __launch_bounds__(256) void attn_mfma(const ushort_t* __restrict__ Qg,
                                                 const ushort_t* __restrict__ Kg,
                                                 const ushort_t* __restrict__ Vtg,
                                                 const float* __restrict__ esc,
                                                 const float* __restrict__ ebi,
                                                 ushort_t* __restrict__ Ab,
                                                 float* __restrict__ unc)
{
    __shared__ __align__(16) ushort_t Kbuf[2][4096];   // 8 blocks x 512 (16 keys x 32 d)
    __shared__ __align__(16) ushort_t Vbuf[2][4096];   // 8 blocks x 512 (16 d x 32 keys, perm)

    const int t    = threadIdx.x;
    const int lane = t & 63, w = t >> 6;
    const int lm   = lane & 15, quad = lane >> 4;
    const int qt   = blockIdx.x & 31;
    const int bh   = blockIdx.x >> 5;
    const int q0   = qt * 64;

    const float scale = esc[0];
    const float bias1 = 1.0f + ebi[0];

    // Q frags (used as B operand: col = q = lm, k = d chunk quad*8); Q pre-scaled
    bf16x8 qa[2];
#pragma unroll
    for (int kc = 0; kc < 2; ++kc)
        qa[kc] = *(const bf16x8*)(Qg + (size_t)(bh * SQ + q0 + w * 16 + lm) * 64
                                  + kc * 32 + quad * 8);

    bf16x8 onesA;
#pragma unroll
    for (int j = 0; j < 8; ++j) onesA[j] = (short)0x3F80;   // bf16 1.0

    const f32x4 fz = {0.f, 0.f, 0.f, 0.f};
    f32x4 acc[4];
#pragma unroll
    for (int nd = 0; nd < 4; ++nd) acc[nd] = fz;
    f32x4 acc1 = fz;

    // V staging key-chunk permutation: quad -> key offset {0,16,8,24}
    const int vq = ((quad & 1) << 4) + ((quad >> 1) << 3);

    auto stage = [&](int kt, int b) {
        const ushort_t* kg = Kg + (size_t)(bh * SQ + kt * 64 + w * 16 + lm) * 64 + quad * 8;
        gld16(kg,      &Kbuf[b][(w * 2 + 0) * 512]);
        gld16(kg + 32, &Kbuf[b][(w * 2 + 1) * 512]);
        const ushort_t* vg = Vtg + (size_t)bh * 64 * SQ + (size_t)(w * 16 + lm) * SQ
                           + kt * 64 + vq;
        gld16(vg,      &Vbuf[b][(w * 2 + 0) * 512]);
        gld16(vg + 32, &Vbuf[b][(w * 2 + 1) * 512]);
    };

    stage(0, 0);
    int cur = 0;
    const bool odd = (quad & 1) != 0;
    for (int kt = 0; kt < 32; ++kt) {
        __syncthreads();              // drains buf[cur]; frees buf[cur^1]
        if (kt + 1 < 32) stage(kt + 1, cur ^ 1);
        const ushort_t* Kc = Kbuf[cur];
        const ushort_t* Vc = Vbuf[cur];

#pragma unroll
        for (int hc = 0; hc < 2; ++hc) {
            // S^T for key groups g = hc*2 + {0,1}: lane holds keys g*16+quad*4+r, q=lm
            f32x4 st0 = fz, st1 = fz;
#pragma unroll
            for (int kc = 0; kc < 2; ++kc) {
                bf16x8 kb0 = *(const bf16x8*)&Kc[((hc * 2 + 0) * 2 + kc) * 512 + lane * 8];
                bf16x8 kb1 = *(const bf16x8*)&Kc[((hc * 2 + 1) * 2 + kc) * 512 + lane * 8];
                st0 = __builtin_amdgcn_mfma_f32_16x16x32_bf16(kb0, qa[kc], st0, 0, 0, 0);
                st1 = __builtin_amdgcn_mfma_f32_16x16x32_bf16(kb1, qa[kc], st1, 0, 0, 0);
            }
            // evidence = exp(s)*scale + bias1, packed to bf16 dwords (2 keys each)
            unsigned pk0[2], pk1[2];
#pragma unroll
            for (int p = 0; p < 2; ++p) {
                float a0 = fmaf(__expf(st0[2 * p]),     scale, bias1);
                float a1 = fmaf(__expf(st0[2 * p + 1]), scale, bias1);
                float b0 = fmaf(__expf(st1[2 * p]),     scale, bias1);
                float b1 = fmaf(__expf(st1[2 * p + 1]), scale, bias1);
                asm("v_cvt_pk_bf16_f32 %0, %1, %2" : "=v"(pk0[p]) : "v"(a0), "v"(a1));
                asm("v_cvt_pk_bf16_f32 %0, %1, %2" : "=v"(pk1[p]) : "v"(b0), "v"(b1));
            }
            // assemble E^T B-frag. Key-slot map (within 32-key half):
            //   quad0: ni0 k0-7 | quad1: ni1 k0-7 (=16-23) | quad2: ni0 k8-15 | quad3: ni1 k8-15 (=24-31)
            // even quads keep ni0 & receive partner's ni0; odd keep ni1 & receive ni1.
            unsigned keep0 = odd ? pk1[0] : pk0[0];
            unsigned keep1 = odd ? pk1[1] : pk0[1];
            unsigned send0 = odd ? pk0[0] : pk1[0];
            unsigned send1 = odd ? pk0[1] : pk1[1];
            unsigned recv0 = (unsigned)__builtin_amdgcn_ds_swizzle((int)send0, 0x401F); // xor 16
            unsigned recv1 = (unsigned)__builtin_amdgcn_ds_swizzle((int)send1, 0x401F);
            u32x4 fv;
            fv[0] = odd ? recv0 : keep0;
            fv[1] = odd ? recv1 : keep1;
            fv[2] = odd ? keep0 : recv0;
            fv[3] = odd ? keep1 : recv1;
            bf16x8 eb = __builtin_bit_cast(bf16x8, fv);
            // acc^T[d][q] += V^T E^T over this key half
#pragma unroll
            for (int nd = 0; nd < 4; ++nd) {
                bf16x8 va = *(const bf16x8*)&Vc[(nd * 2 + hc) * 512 + lane * 8];
                acc[nd] = __builtin_amdgcn_mfma_f32_16x16x32_bf16(va, eb, acc[nd], 0, 0, 0);
            }
            // denominator: ones x E^T -> every lane gets sum_k ev[q=lm]
            acc1 = __builtin_amdgcn_mfma_f32_16x16x32_bf16(onesA, eb, acc1, 0, 0, 0);
        }
        cur ^= 1;
    }

    const float di = 1.0f / acc1[0];
    if (quad == 0)
        unc[(size_t)bh * SQ + q0 + w * 16 + lm] = (float)SQ * di;

    const int b = bh >> 4, h = bh & 15;
    const size_t arow = (size_t)(b * SQ + q0 + w * 16 + lm) * Dm + h * 64;
#pragma unroll
    for (int nd = 0; nd < 4; ++nd) {
        float o0 = acc[nd][0] * di, o1 = acc[nd][1] * di;
        float o2 = acc[nd][2] * di, o3 = acc[nd][3] * di;
        unsigned lo, hi;
        asm("v_cvt_pk_bf16_f32 %0, %1, %2" : "=v"(lo) : "v"(o0), "v"(o1));
        asm("v_cvt_pk_bf16_f32 %0, %1, %2" : "=v"(hi) : "v"(o2), "v"(o3));
        uint2 ov; ov.x = lo; ov.y = hi;
        *(uint2*)&Ab[arow + nd * 16 + quad * 4] = ov;   // d = nd*16+quad*4+r, q row = lm
    }
}

extern "C" void kernel_launch(void* const* d_in, const int* in_sizes, int n_in,
                              void* d_out, int out_size, void* d_ws, size_t ws_size,
                              hipStream_t stream)
{
    const float* x   = (const float*)d_in[0];
    const float* qw  = (const float*)d_in[1];
    const float* qb  = (const float*)d_in[2];
    const float* kw  = (const float*)d_in[3];
    const float* kb  = (const float*)d_in[4];
    const float* vw  = (const float*)d_in[5];
    const float* vb  = (const float*)d_in[6];
    const float* ow  = (const float*)d_in[7];
    const float* ob  = (const float*)d_in[8];
    const float* esc = (const float*)d_in[9];
    const float* ebi = (const float*)d_in[10];

    float* out = (float*)d_out;                 // output 0: [B,S,D] fp32 (16 MB)
    float* unc = out + (size_t)MM * Dm;         // output 1: [B,H,S] fp32

    // ws (24 MB): xb 8MB @0 (reused as Ab) | qwb/kwb/vwb/owb 2MB @8/10/12/14MB | Vb 8MB @16MB
    ushort_t* xb  = (ushort_t*)d_ws;
    ushort_t* qwb = (ushort_t*)((char*)d_ws + (8u  << 20));
    ushort_t* kwb = (ushort_t*)((char*)d_ws + (10u << 20));
    ushort_t* vwb = (ushort_t*)((char*)d_ws + (12u << 20));
    ushort_t* owb = (ushort_t*)((char*)d_ws + (14u << 20));
    ushort_t* Vb  = (ushort_t*)((char*)d_ws + (16u << 20));
    ushort_t* Ab  = xb;                         // xb dead after QKV GEMMs

    // Q,K tiles live in d_out's output-0 region (dead until gemm_out writes it last)
    ushort_t* Qb = (ushort_t*)d_out;
    ushort_t* Kb = Qb + (size_t)MM * Dm;

    cast_all<<<dim3(2097152 / 256), dim3(256), 0, stream>>>(
        (const float4*)x, (const float4*)qw, (const float4*)kw,
        (const float4*)vw, (const float4*)ow,
        (uint2*)xb, (uint2*)qwb, (uint2*)kwb, (uint2*)vwb, (uint2*)owb);

    gemm_qkv<<<dim3(Dm / 128, MM / 128, 3), dim3(256), 0, stream>>>(
        xb, qwb, qb, kwb, kb, vwb, vb, Qb, Kb, Vb);

    attn_mfma<<<dim3(BB * NH * (SQ / 64)), dim3(256), 0, stream>>>(
        Qb, Kb, Vb, esc, ebi, Ab, unc);

    gemm_out<<<dim3(Dm / 128, MM / 64), dim3(256), 0, stream>>>(Ab, owb, ob, out);
}